// Round 16
// baseline (555.207 us; speedup 1.0000x reference)
//
#include <hip/hip_runtime.h>
#include <hip/hip_bf16.h>

#define N_NODES 100000
#define N_EDGES 200000
#define N_GRAPHS 4096
#define NODE_DIM 64
#define HID 256
#define N_GAT 4
#define NEG_SLOPE 0.2f
#define EPS 1e-9f
#define NB 98  // ceil(N_NODES/1024)

typedef const __attribute__((address_space(1))) void gv_t;
typedef __attribute__((address_space(3))) void lv_t;
typedef __attribute__((ext_vector_type(8))) short bf16x8;
typedef __attribute__((ext_vector_type(4))) float f32x4;

__device__ __forceinline__ float b2f(unsigned short u) {
    return __uint_as_float(((unsigned)u) << 16);
}
__device__ __forceinline__ unsigned short f2b(float f) {   // RNE
    unsigned u = __float_as_uint(f);
    return (unsigned short)((u + 0x7fffu + ((u >> 16) & 1u)) >> 16);
}

// ==================== converters ====================
__global__ void convert_f32_bf16(const float* __restrict__ src,
                                 unsigned short* __restrict__ dst, int n4) {
    int i = blockIdx.x * 256 + threadIdx.x;
    if (i >= n4) return;
    float4 v = ((const float4*)src)[i];
    ushort4 o;
    o.x = f2b(v.x); o.y = f2b(v.y); o.z = f2b(v.z); o.w = f2b(v.w);
    ((ushort4*)dst)[i] = o;
}

// Wt[c][k] = bf16(W[k][c]);  W is [K][256], Wt is [256][K].  blockIdx.z = layer.
__global__ __launch_bounds__(256) void transpose_bf16(const float* __restrict__ W0,
                                                      unsigned short* __restrict__ Wt0,
                                                      int K) {
    const float* W = W0 + (size_t)blockIdx.z * K * HID;
    unsigned short* Wt = Wt0 + (size_t)blockIdx.z * K * HID;
    __shared__ float tile[32][33];
    const int kb = blockIdx.x * 32, cb = blockIdx.y * 32;
    const int tr = threadIdx.x >> 5, tc = threadIdx.x & 31;
#pragma unroll
    for (int i = 0; i < 4; ++i)
        tile[tr + i * 8][tc] = W[(size_t)(kb + tr + i * 8) * HID + cb + tc];
    __syncthreads();
#pragma unroll
    for (int i = 0; i < 4; ++i)
        Wt[(size_t)(cb + tr + i * 8) * K + kb + tc] = f2b(tile[tc][tr + i * 8]);
}

// wal[l][k] = sum_c Wt[l][c][k]*al[l][c]  (el = z@al = h@(W@al)); same for war.
__global__ __launch_bounds__(256) void precompute_av(const unsigned short* __restrict__ Wt4,
                                                     const float* __restrict__ gal,
                                                     const float* __restrict__ gar,
                                                     float* __restrict__ wal,
                                                     float* __restrict__ war) {
    const int l = blockIdx.x, k = threadIdx.x;
    const unsigned short* Wt = Wt4 + (size_t)l * HID * HID;
    const float* al = gal + l * HID;
    const float* ar = gar + l * HID;
    float a = 0.f, b = 0.f;
    for (int c = 0; c < HID; ++c) {
        float w = b2f(Wt[(size_t)c * HID + k]);
        a = fmaf(w, al[c], a);
        b = fmaf(w, ar[c], b);
    }
    wal[l * HID + k] = a;
    war[l * HID + k] = b;
}

// ==================== MFMA GEMM ====================
// Y[M,256] = X[M,K](bf16) @ Wt[256,K](bf16, pre-transposed) (+bias).
// 128x128 block tile, 4 waves (64x64 each), 4x4 frags of 16x16x32 bf16 MFMA.
// SINGLE-buffered LDS (32KB) -> 5 blocks/CU; natural VGPR allocation (88).
// 1D grid, bijective XCD swizzle, col-half = fast bit (L2 X-reuse).
// Epilogue: acc -> bank-swizzled LDS bf16 tile (32KB scratch) -> 16B stores.
template <int K, bool BIAS>
__global__ __launch_bounds__(256) void gemm_mfma(const unsigned short* __restrict__ Xb,
                                                 const unsigned short* __restrict__ Wt,
                                                 const float* __restrict__ bias,
                                                 unsigned short* __restrict__ Yb,
                                                 int M) {
    constexpr int KC = 64;
    constexpr int NT = K / KC;
    __shared__ unsigned short sb[2][128 * KC];   // [0]=X tile, [1]=W tile; 32KB total
    const int t = threadIdx.x, wv = t >> 6, ln = t & 63;
    const int wr2 = wv >> 1, wc2 = wv & 1;       // wave quadrant (2x2)

    // bijective XCD swizzle of flattened block id (m204 formula)
    const int nwg = gridDim.x;
    const int q8 = nwg >> 3, r8 = nwg & 7;
    const int xcd = blockIdx.x & 7, idx = blockIdx.x >> 3;
    const int sw = (xcd < r8) ? xcd * (q8 + 1) + idx : r8 * (q8 + 1) + (xcd - r8) * q8 + idx;
    const long row0 = (long)(sw >> 1) * 128;
    const int  col0 = (sw & 1) * 128;

    f32x4 acc[4][4];
#pragma unroll
    for (int m = 0; m < 4; ++m)
#pragma unroll
        for (int n = 0; n < 4; ++n) acc[m][n] = (f32x4){0.f, 0.f, 0.f, 0.f};

#pragma unroll
    for (int tt = 0; tt < NT; ++tt) {
        const int k0 = tt * KC;
        // ---- stage X + W tiles (16 chunks of 1KB each, 4/wave) ----
#pragma unroll
        for (int i = 0; i < 4; ++i) {
            const int chunk = wv * 4 + i;
            const int row = chunk * 8 + (ln >> 3);
            const int gsrc = (ln & 7) ^ (row & 7);
            long gr = row0 + row; if (gr >= M) gr = M - 1;
            const unsigned short* gp = Xb + gr * K + k0 + gsrc * 8;
            __builtin_amdgcn_global_load_lds((gv_t*)gp, (lv_t*)(&sb[0][chunk * 512 + ln * 8]), 16, 0, 0);
        }
#pragma unroll
        for (int i = 0; i < 4; ++i) {
            const int chunk = wv * 4 + i;
            const int row = chunk * 8 + (ln >> 3);
            const int gsrc = (ln & 7) ^ (row & 7);
            const unsigned short* gp = Wt + (size_t)(col0 + row) * K + k0 + gsrc * 8;
            __builtin_amdgcn_global_load_lds((gv_t*)gp, (lv_t*)(&sb[1][chunk * 512 + ln * 8]), 16, 0, 0);
        }
        __syncthreads();   // drain staging

#pragma unroll
        for (int kk = 0; kk < 2; ++kk) {
            bf16x8 a[4], b[4];
            const int g = kk * 4 + (ln >> 4);
#pragma unroll
            for (int m = 0; m < 4; ++m) {
                const int row = wr2 * 64 + m * 16 + (ln & 15);
                const int s = g ^ (row & 7);
                a[m] = *(const bf16x8*)&sb[0][row * 64 + s * 8];
            }
#pragma unroll
            for (int n = 0; n < 4; ++n) {
                const int row = wc2 * 64 + n * 16 + (ln & 15);
                const int s = g ^ (row & 7);
                b[n] = *(const bf16x8*)&sb[1][row * 64 + s * 8];
            }
#pragma unroll
            for (int m = 0; m < 4; ++m)
#pragma unroll
                for (int n = 0; n < 4; ++n)
                    acc[m][n] = __builtin_amdgcn_mfma_f32_16x16x32_bf16(a[m], b[n], acc[m][n], 0, 0, 0);
        }
        __syncthreads();   // protect buffer reuse (next stage / epilogue)
    }

    // ---- epilogue: acc -> LDS bf16 tile (bank-swizzled) -> coalesced stores ----
    float bj[4];
#pragma unroll
    for (int n = 0; n < 4; ++n)
        bj[n] = BIAS ? bias[col0 + wc2 * 64 + n * 16 + (ln & 15)] : 0.f;

    char* ep = (char*)&sb[0][0];   // 32KB = full 128x128 bf16 tile
#pragma unroll
    for (int m = 0; m < 4; ++m) {
        const int rb = wr2 * 64 + m * 16 + 4 * (ln >> 4);
#pragma unroll
        for (int n = 0; n < 4; ++n) {
            const int colB = (wc2 * 64 + n * 16 + (ln & 15)) * 2;
#pragma unroll
            for (int qq = 0; qq < 4; ++qq) {
                const int rr = rb + qq;
                *(unsigned short*)(ep + rr * 256 + (colB ^ ((rr & 7) << 4))) = f2b(acc[m][n][qq] + bj[n]);
            }
        }
    }
    __syncthreads();
#pragma unroll
    for (int j = 0; j < 8; ++j) {
        const int row = t >> 1;
        const int cb = (t & 1) * 128 + j * 16;               // col byte within row
        uint4 v = *(const uint4*)(ep + row * 256 + (cb ^ ((row & 7) << 4)));
        const long r = row0 + row;
        if (r < M) *(uint4*)(Yb + r * HID + col0 + (cb >> 1)) = v;
    }
}

// ======================= CSR build (per launch) =======================
__global__ void hist_dst(const int* __restrict__ dst, int* __restrict__ deg) {
    int i = blockIdx.x * 256 + threadIdx.x;
    if (i < N_EDGES) atomicAdd(&deg[dst[i]], 1);
}

__global__ __launch_bounds__(1024) void scan_block(const int* __restrict__ deg,
                                                   int* __restrict__ sexc,
                                                   int* __restrict__ bsum) {
    int t = threadIdx.x, gid = blockIdx.x * 1024 + t;
    int v = (gid < N_NODES) ? deg[gid] : 0;
    int lane = t & 63, wv = t >> 6;
    int x = v;
#pragma unroll
    for (int o = 1; o < 64; o <<= 1) {
        int y = __shfl_up(x, o);
        if (lane >= o) x += y;
    }
    __shared__ int wsum[16];
    if (lane == 63) wsum[wv] = x;
    __syncthreads();
    if (t == 0) {
        int a = 0;
#pragma unroll
        for (int i = 0; i < 16; ++i) { int tt = wsum[i]; wsum[i] = a; a += tt; }
        bsum[blockIdx.x] = a;
    }
    __syncthreads();
    sexc[gid] = (x - v) + wsum[wv];
}

__global__ __launch_bounds__(128) void scan_partials(int* __restrict__ bsum,
                                                     int* __restrict__ offsets) {
    __shared__ int s[128];
    int t = threadIdx.x;
    int v = (t < NB) ? bsum[t] : 0;
    s[t] = v;
    __syncthreads();
    for (int o = 1; o < 128; o <<= 1) {
        int y = (t >= o) ? s[t - o] : 0;
        __syncthreads();
        s[t] += y;
        __syncthreads();
    }
    if (t < NB) bsum[t] = s[t] - v;
    if (t == 127) offsets[N_NODES] = s[127];
}

// writes offsets AND initializes cnt (= next free slot) in one pass
__global__ __launch_bounds__(1024) void scan_add(const int* __restrict__ sexc,
                                                 const int* __restrict__ bsum,
                                                 int* __restrict__ offsets,
                                                 int* __restrict__ cnt) {
    int gid = blockIdx.x * 1024 + threadIdx.x;
    if (gid < N_NODES) {
        int v = sexc[gid] + bsum[blockIdx.x];
        offsets[gid] = v;
        cnt[gid] = v;
    }
}

__global__ void csr_fill(const int* __restrict__ src, const int* __restrict__ dst,
                         int* __restrict__ cnt, int* __restrict__ csrc) {
    int i = blockIdx.x * 256 + threadIdx.x;
    if (i < N_EDGES) {
        int slot = atomicAdd(&cnt[dst[i]], 1);
        csrc[slot] = src[i];
    }
}

// goff[g] = lower_bound(graph_ids, g); graph_ids is sorted.
__global__ void graph_offsets(const int* __restrict__ gid, int* __restrict__ goff) {
    int g = blockIdx.x * 256 + threadIdx.x;
    if (g > N_GRAPHS) return;
    int lo = 0, hi = N_NODES;
    while (lo < hi) {
        int mid = (lo + hi) >> 1;
        if (gid[mid] < g) lo = mid + 1; else hi = mid;
    }
    goff[g] = lo;
}

// ===================== per-layer small kernels =====================
// el[n] = h[n]·wal, er[n] = h[n]·war for bf16 h. One wave per node.
__global__ void node_dots_b(const unsigned short* __restrict__ h,
                            const float* __restrict__ wal,
                            const float* __restrict__ war,
                            float* __restrict__ el, float* __restrict__ er) {
    int n = blockIdx.x * 4 + (threadIdx.x >> 6);
    int lane = threadIdx.x & 63;
    ushort4 zz = ((const ushort4*)(h + (size_t)n * HID))[lane];
    float4 a = ((const float4*)wal)[lane];
    float4 b = ((const float4*)war)[lane];
    float pl = b2f(zz.x) * a.x + b2f(zz.y) * a.y + b2f(zz.z) * a.z + b2f(zz.w) * a.w;
    float pr = b2f(zz.x) * b.x + b2f(zz.y) * b.y + b2f(zz.z) * b.z + b2f(zz.w) * b.w;
#pragma unroll
    for (int off = 32; off > 0; off >>= 1) {
        pl += __shfl_down(pl, off);
        pr += __shfl_down(pr, off);
    }
    if (lane == 0) { el[n] = pl; er[n] = pr; }
}

// One wave per dst node: FUSED softmax + gather + residual + ReLU + next dots.
// Softmax is computed REDUNDANTLY by every lane in scalar registers (deg is
// Poisson(2); DMAX=8 covers 99.9% of nodes) — zero cross-lane ops, and the
// edge metadata loads batch into two parallel rounds (csrc[], then elin[]).
// el/er are double-buffered across layers to avoid the fused read/write race.
__global__ __launch_bounds__(256) void gather_attn(const int* __restrict__ offs,
                                                   const int* __restrict__ csrc,
                                                   const float* __restrict__ elin,
                                                   const float* __restrict__ erin,
                                                   const unsigned short* __restrict__ z,
                                                   unsigned short* __restrict__ Ab,
                                                   const float* __restrict__ waln,
                                                   const float* __restrict__ warn,
                                                   float* __restrict__ elout,
                                                   float* __restrict__ erout) {
    constexpr int DMAX = 8;
    const int n = blockIdx.x * 4 + (threadIdx.x >> 6);
    const int lane = threadIdx.x & 63;
    const int beg = offs[n], end = offs[n + 1];
    const int deg = end - beg;
    const int d = deg < DMAX ? deg : DMAX;
    const float ern = erin[n];

    // round 1: edge sources (parallel loads, statically indexed regs)
    int sc[DMAX];
#pragma unroll
    for (int i = 0; i < DMAX; ++i) sc[i] = (i < d) ? csrc[beg + i] : 0;

    // round 2: el gathers (uniform-address broadcast loads, parallel)
    float vv[DMAX];
#pragma unroll
    for (int i = 0; i < DMAX; ++i) {
        if (i < d) {
            float v = elin[sc[i]] + ern;
            vv[i] = (v >= 0.f) ? v : NEG_SLOPE * v;
        } else {
            vv[i] = -3.4e38f;
        }
    }

    // scalar softmax (pure ALU, no cross-lane)
    float m = -3.4e38f;
#pragma unroll
    for (int i = 0; i < DMAX; ++i) m = fmaxf(m, vv[i]);
    for (int c = beg + DMAX; c < end; ++c) {               // deg>8: ~0.1%
        float v = elin[csrc[c]] + ern;
        v = (v >= 0.f) ? v : NEG_SLOPE * v;
        m = fmaxf(m, v);
    }
    float aa[DMAX];
    float s = 0.f;
#pragma unroll
    for (int i = 0; i < DMAX; ++i) {
        aa[i] = (i < d) ? __expf(vv[i] - m) : 0.f;
        s += aa[i];
    }
    for (int c = beg + DMAX; c < end; ++c) {
        float v = elin[csrc[c]] + ern;
        v = (v >= 0.f) ? v : NEG_SLOPE * v;
        s += __expf(v - m);
    }
    const float inv = 1.f / (s + EPS);

    // weighted gather (alpha from registers)
    float4 acc = make_float4(0.f, 0.f, 0.f, 0.f);
#pragma unroll
    for (int i = 0; i < DMAX; ++i) {
        if (i < d) {
            float a = aa[i] * inv;
            ushort4 zz = ((const ushort4*)(z + (size_t)sc[i] * HID))[lane];
            acc.x = fmaf(a, b2f(zz.x), acc.x);
            acc.y = fmaf(a, b2f(zz.y), acc.y);
            acc.z = fmaf(a, b2f(zz.z), acc.z);
            acc.w = fmaf(a, b2f(zz.w), acc.w);
        }
    }
    for (int c = beg + DMAX; c < end; ++c) {               // deg>8: ~0.1%
        int scc = csrc[c];
        float v = elin[scc] + ern;
        v = (v >= 0.f) ? v : NEG_SLOPE * v;
        float a = __expf(v - m) * inv;
        ushort4 zz = ((const ushort4*)(z + (size_t)scc * HID))[lane];
        acc.x = fmaf(a, b2f(zz.x), acc.x);
        acc.y = fmaf(a, b2f(zz.y), acc.y);
        acc.z = fmaf(a, b2f(zz.z), acc.z);
        acc.w = fmaf(a, b2f(zz.w), acc.w);
    }

    // residual + ReLU + bf16 write
    ushort4* Ap = (ushort4*)(Ab + (size_t)n * HID);
    ushort4 hh = Ap[lane];
    float h0 = fmaxf(b2f(hh.x) + acc.x, 0.f);
    float h1 = fmaxf(b2f(hh.y) + acc.y, 0.f);
    float h2 = fmaxf(b2f(hh.z) + acc.z, 0.f);
    float h3 = fmaxf(b2f(hh.w) + acc.w, 0.f);
    ushort4 ob;
    ob.x = f2b(h0); ob.y = f2b(h1); ob.z = f2b(h2); ob.w = f2b(h3);
    Ap[lane] = ob;

    if (waln) {   // wave-uniform: next layer's attention dots into the OTHER buffer
        float4 wa = ((const float4*)waln)[lane];
        float4 wb = ((const float4*)warn)[lane];
        float pl = h0 * wa.x + h1 * wa.y + h2 * wa.z + h3 * wa.w;
        float pr = h0 * wb.x + h1 * wb.y + h2 * wb.z + h3 * wb.w;
#pragma unroll
        for (int o = 32; o > 0; o >>= 1) {
            pl += __shfl_down(pl, o);
            pr += __shfl_down(pr, o);
        }
        if (lane == 0) { elout[n] = pl; erout[n] = pr; }
    }
}

// g[gi,:] = sum of bf16 h rows in [goff[gi], goff[gi+1]) — sorted, no atomics
__global__ __launch_bounds__(256) void pool_seg(const unsigned short* __restrict__ h,
                                                const int* __restrict__ goff,
                                                float* __restrict__ g) {
    const int gi = blockIdx.x, t = threadIdx.x;
    const int beg = goff[gi], end = goff[gi + 1];
    float acc = 0.f;
    for (int n = beg; n < end; ++n) acc += b2f(h[(size_t)n * HID + t]);
    g[(size_t)gi * HID + t] = acc;
}

// fused MLP: relu(g@w1+b1) -> relu(@w2+b2) -> @w3+b3
__global__ void mlp_kernel(const float* __restrict__ g,
                           const float* __restrict__ w1, const float* __restrict__ b1,
                           const float* __restrict__ w2, const float* __restrict__ b2,
                           const float* __restrict__ w3, const float* __restrict__ b3,
                           float* __restrict__ out) {
    int gi = blockIdx.x, t = threadIdx.x;
    __shared__ float x[HID];
    __shared__ float y1[HID / 2];
    __shared__ float y2[HID / 4];
    x[t] = g[gi * HID + t];
    __syncthreads();
    if (t < HID / 2) {
        float a = b1[t];
#pragma unroll 8
        for (int k = 0; k < HID; ++k) a += x[k] * w1[k * (HID / 2) + t];
        y1[t] = fmaxf(a, 0.f);
    }
    __syncthreads();
    if (t < HID / 4) {
        float a = b2[t];
#pragma unroll 8
        for (int k = 0; k < HID / 2; ++k) a += y1[k] * w2[k * (HID / 4) + t];
        y2[t] = fmaxf(a, 0.f);
    }
    __syncthreads();
    if (t < 64) {
        float p = y2[t] * w3[t];
#pragma unroll
        for (int off = 32; off > 0; off >>= 1) p += __shfl_down(p, off);
        if (t == 0) out[gi] = p + b3[0];
    }
}

extern "C" void kernel_launch(void* const* d_in, const int* in_sizes, int n_in,
                              void* d_out, int out_size, void* d_ws, size_t ws_size,
                              hipStream_t stream) {
    const float* node_feats = (const float*)d_in[0];
    const int*   src        = (const int*)d_in[1];
    const int*   dst        = (const int*)d_in[2];
    const int*   graph_ids  = (const int*)d_in[3];
    const float* w_embed    = (const float*)d_in[4];
    const float* b_embed    = (const float*)d_in[5];
    const float* gat_W      = (const float*)d_in[6];
    const float* gat_al     = (const float*)d_in[7];
    const float* gat_ar     = (const float*)d_in[8];
    const float* w1         = (const float*)d_in[9];
    const float* b1         = (const float*)d_in[10];
    const float* w2         = (const float*)d_in[11];
    const float* b2         = (const float*)d_in[12];
    const float* w3         = (const float*)d_in[13];
    const float* b3         = (const float*)d_in[14];
    float* out = (float*)d_out;

    char* ws = (char*)d_ws;
    size_t off = 0;
    auto alloc = [&](size_t bytes) { char* p = ws + off; off += (bytes + 255) & ~size_t(255); return p; };
    unsigned short* Ab      = (unsigned short*)alloc((size_t)N_NODES * HID * 2); // h (bf16)
    unsigned short* Zb      = (unsigned short*)alloc((size_t)N_NODES * HID * 2); // z (bf16); aliases nfb
    unsigned short* Wte     = (unsigned short*)alloc((size_t)HID * NODE_DIM * 2);// embed W^T bf16
    unsigned short* Wtg     = (unsigned short*)alloc((size_t)N_GAT * HID * HID * 2); // GAT W^T bf16 (all layers)
    float*          wal     = (float*)alloc((size_t)N_GAT * HID * 4);            // W@al per layer
    float*          war     = (float*)alloc((size_t)N_GAT * HID * 4);            // W@ar per layer
    float*          eler0   = (float*)alloc((size_t)2 * N_NODES * 4);            // el|er buffer A
    float*          eler1   = (float*)alloc((size_t)2 * N_NODES * 4);            // el|er buffer B
    int*            deg     = (int*)alloc((size_t)N_NODES * 4);
    int*            cnt     = (int*)alloc((size_t)N_NODES * 4);
    int*            sexc    = (int*)alloc((size_t)NB * 1024 * 4);
    int*            bsum    = (int*)alloc(128 * 4);
    int*            offsets = (int*)alloc((size_t)(N_NODES + 1) * 4);
    int*            csrc    = (int*)alloc((size_t)N_EDGES * 4);
    int*            goff    = (int*)alloc((size_t)(N_GRAPHS + 1) * 4);
    float*          g       = (float*)alloc((size_t)N_GRAPHS * HID * 4);
    float*          el0 = eler0,          *er0 = eler0 + N_NODES;
    float*          el1 = eler1,          *er1 = eler1 + N_NODES;
    unsigned short* nfb     = Zb;  // node_feats bf16, dead before Zb first written

    // ---- CSR build + graph offsets (graph static across layers) ----
    hipMemsetAsync(deg, 0, (size_t)N_NODES * 4, stream);
    hist_dst<<<(N_EDGES + 255) / 256, 256, 0, stream>>>(dst, deg);
    scan_block<<<NB, 1024, 0, stream>>>(deg, sexc, bsum);
    scan_partials<<<1, 128, 0, stream>>>(bsum, offsets);
    scan_add<<<NB, 1024, 0, stream>>>(sexc, bsum, offsets, cnt);
    csr_fill<<<(N_EDGES + 255) / 256, 256, 0, stream>>>(src, dst, cnt, csrc);
    graph_offsets<<<(N_GRAPHS + 256) / 256, 256, 0, stream>>>(graph_ids, goff);

    // ---- all weight prep up front ----
    transpose_bf16<<<dim3(NODE_DIM / 32, HID / 32, 1), 256, 0, stream>>>(w_embed, Wte, NODE_DIM);
    transpose_bf16<<<dim3(HID / 32, HID / 32, N_GAT), 256, 0, stream>>>(gat_W, Wtg, HID);
    precompute_av<<<N_GAT, 256, 0, stream>>>(Wtg, gat_al, gat_ar, wal, war);
    convert_f32_bf16<<<(N_NODES * NODE_DIM / 4 + 255) / 256, 256, 0, stream>>>(node_feats, nfb, N_NODES * NODE_DIM / 4);

    const int ntm = (N_NODES + 127) / 128;       // 782 M-tiles
    const int ngrid = ntm * 2;                   // x2 column halves (1D, swizzled)

    // ---- embed: h = nf @ w_embed + b; then layer-0 el/er (buffer A) ----
    gemm_mfma<NODE_DIM, true><<<ngrid, 256, 0, stream>>>(nfb, Wte, b_embed, Ab, N_NODES);
    node_dots_b<<<N_NODES / 4, 256, 0, stream>>>(Ab, wal, war, el0, er0);

    for (int l = 0; l < N_GAT; ++l) {
        gemm_mfma<HID, false><<<ngrid, 256, 0, stream>>>(
            Ab, Wtg + (size_t)l * HID * HID, nullptr, Zb, N_NODES);
        const bool odd = (l & 1);
        const float* elin = odd ? el1 : el0;
        const float* erin = odd ? er1 : er0;
        float* elout = odd ? el0 : el1;
        float* erout = odd ? er0 : er1;
        const float* waln = (l < N_GAT - 1) ? wal + (l + 1) * HID : nullptr;
        const float* warn = (l < N_GAT - 1) ? war + (l + 1) * HID : nullptr;
        gather_attn<<<N_NODES / 4, 256, 0, stream>>>(offsets, csrc, elin, erin, Zb, Ab,
                                                     waln, warn, elout, erout);
    }

    pool_seg<<<N_GRAPHS, 256, 0, stream>>>(Ab, goff, g);
    mlp_kernel<<<N_GRAPHS, HID, 0, stream>>>(g, w1, b1, w2, b2, w3, b3, out);
}

// Round 17
// 497.545 us; speedup vs baseline: 1.1159x; 1.1159x over previous
//
#include <hip/hip_runtime.h>
#include <hip/hip_bf16.h>

#define N_NODES 100000
#define N_EDGES 200000
#define N_GRAPHS 4096
#define NODE_DIM 64
#define HID 256
#define N_GAT 4
#define NEG_SLOPE 0.2f
#define EPS 1e-9f
#define NB 98  // ceil(N_NODES/1024)

typedef const __attribute__((address_space(1))) void gv_t;
typedef __attribute__((address_space(3))) void lv_t;
typedef __attribute__((ext_vector_type(8))) short bf16x8;
typedef __attribute__((ext_vector_type(4))) float f32x4;

__device__ __forceinline__ float b2f(unsigned short u) {
    return __uint_as_float(((unsigned)u) << 16);
}
__device__ __forceinline__ unsigned short f2b(float f) {   // RNE
    unsigned u = __float_as_uint(f);
    return (unsigned short)((u + 0x7fffu + ((u >> 16) & 1u)) >> 16);
}

// ==================== converters ====================
__global__ void convert_f32_bf16(const float* __restrict__ src,
                                 unsigned short* __restrict__ dst, int n4) {
    int i = blockIdx.x * 256 + threadIdx.x;
    if (i >= n4) return;
    float4 v = ((const float4*)src)[i];
    ushort4 o;
    o.x = f2b(v.x); o.y = f2b(v.y); o.z = f2b(v.z); o.w = f2b(v.w);
    ((ushort4*)dst)[i] = o;
}

// Wt[c][k] = bf16(W[k][c]);  W is [K][256], Wt is [256][K].  blockIdx.z = layer.
__global__ __launch_bounds__(256) void transpose_bf16(const float* __restrict__ W0,
                                                      unsigned short* __restrict__ Wt0,
                                                      int K) {
    const float* W = W0 + (size_t)blockIdx.z * K * HID;
    unsigned short* Wt = Wt0 + (size_t)blockIdx.z * K * HID;
    __shared__ float tile[32][33];
    const int kb = blockIdx.x * 32, cb = blockIdx.y * 32;
    const int tr = threadIdx.x >> 5, tc = threadIdx.x & 31;
#pragma unroll
    for (int i = 0; i < 4; ++i)
        tile[tr + i * 8][tc] = W[(size_t)(kb + tr + i * 8) * HID + cb + tc];
    __syncthreads();
#pragma unroll
    for (int i = 0; i < 4; ++i)
        Wt[(size_t)(cb + tr + i * 8) * K + kb + tc] = f2b(tile[tc][tr + i * 8]);
}

// wal[l][k] = sum_c Wt[l][c][k]*al[l][c]  (el = z@al = h@(W@al)); same for war.
__global__ __launch_bounds__(256) void precompute_av(const unsigned short* __restrict__ Wt4,
                                                     const float* __restrict__ gal,
                                                     const float* __restrict__ gar,
                                                     float* __restrict__ wal,
                                                     float* __restrict__ war) {
    const int l = blockIdx.x, k = threadIdx.x;
    const unsigned short* Wt = Wt4 + (size_t)l * HID * HID;
    const float* al = gal + l * HID;
    const float* ar = gar + l * HID;
    float a = 0.f, b = 0.f;
    for (int c = 0; c < HID; ++c) {
        float w = b2f(Wt[(size_t)c * HID + k]);
        a = fmaf(w, al[c], a);
        b = fmaf(w, ar[c], b);
    }
    wal[l * HID + k] = a;
    war[l * HID + k] = b;
}

// ==================== MFMA GEMM ====================
// Y[M,256] = X[M,K](bf16) @ Wt[256,K](bf16, pre-transposed) (+bias).
// 128x128 block tile, 4 waves (64x64 each), 4x4 frags of 16x16x32 bf16 MFMA.
// SINGLE-buffered LDS (32KB) -> 5 blocks/CU; natural VGPR allocation (88).
// 1D grid, bijective XCD swizzle, col-half = fast bit (L2 X-reuse).
// Epilogue: acc -> bank-swizzled LDS bf16 tile (32KB scratch) -> 16B stores.
template <int K, bool BIAS>
__global__ __launch_bounds__(256) void gemm_mfma(const unsigned short* __restrict__ Xb,
                                                 const unsigned short* __restrict__ Wt,
                                                 const float* __restrict__ bias,
                                                 unsigned short* __restrict__ Yb,
                                                 int M) {
    constexpr int KC = 64;
    constexpr int NT = K / KC;
    __shared__ unsigned short sb[2][128 * KC];   // [0]=X tile, [1]=W tile; 32KB total
    const int t = threadIdx.x, wv = t >> 6, ln = t & 63;
    const int wr2 = wv >> 1, wc2 = wv & 1;       // wave quadrant (2x2)

    // bijective XCD swizzle of flattened block id (m204 formula)
    const int nwg = gridDim.x;
    const int q8 = nwg >> 3, r8 = nwg & 7;
    const int xcd = blockIdx.x & 7, idx = blockIdx.x >> 3;
    const int sw = (xcd < r8) ? xcd * (q8 + 1) + idx : r8 * (q8 + 1) + (xcd - r8) * q8 + idx;
    const long row0 = (long)(sw >> 1) * 128;
    const int  col0 = (sw & 1) * 128;

    f32x4 acc[4][4];
#pragma unroll
    for (int m = 0; m < 4; ++m)
#pragma unroll
        for (int n = 0; n < 4; ++n) acc[m][n] = (f32x4){0.f, 0.f, 0.f, 0.f};

#pragma unroll
    for (int tt = 0; tt < NT; ++tt) {
        const int k0 = tt * KC;
        // ---- stage X + W tiles (16 chunks of 1KB each, 4/wave) ----
#pragma unroll
        for (int i = 0; i < 4; ++i) {
            const int chunk = wv * 4 + i;
            const int row = chunk * 8 + (ln >> 3);
            const int gsrc = (ln & 7) ^ (row & 7);
            long gr = row0 + row; if (gr >= M) gr = M - 1;
            const unsigned short* gp = Xb + gr * K + k0 + gsrc * 8;
            __builtin_amdgcn_global_load_lds((gv_t*)gp, (lv_t*)(&sb[0][chunk * 512 + ln * 8]), 16, 0, 0);
        }
#pragma unroll
        for (int i = 0; i < 4; ++i) {
            const int chunk = wv * 4 + i;
            const int row = chunk * 8 + (ln >> 3);
            const int gsrc = (ln & 7) ^ (row & 7);
            const unsigned short* gp = Wt + (size_t)(col0 + row) * K + k0 + gsrc * 8;
            __builtin_amdgcn_global_load_lds((gv_t*)gp, (lv_t*)(&sb[1][chunk * 512 + ln * 8]), 16, 0, 0);
        }
        __syncthreads();   // drain staging

#pragma unroll
        for (int kk = 0; kk < 2; ++kk) {
            bf16x8 a[4], b[4];
            const int g = kk * 4 + (ln >> 4);
#pragma unroll
            for (int m = 0; m < 4; ++m) {
                const int row = wr2 * 64 + m * 16 + (ln & 15);
                const int s = g ^ (row & 7);
                a[m] = *(const bf16x8*)&sb[0][row * 64 + s * 8];
            }
#pragma unroll
            for (int n = 0; n < 4; ++n) {
                const int row = wc2 * 64 + n * 16 + (ln & 15);
                const int s = g ^ (row & 7);
                b[n] = *(const bf16x8*)&sb[1][row * 64 + s * 8];
            }
#pragma unroll
            for (int m = 0; m < 4; ++m)
#pragma unroll
                for (int n = 0; n < 4; ++n)
                    acc[m][n] = __builtin_amdgcn_mfma_f32_16x16x32_bf16(a[m], b[n], acc[m][n], 0, 0, 0);
        }
        __syncthreads();   // protect buffer reuse (next stage / epilogue)
    }

    // ---- epilogue: acc -> LDS bf16 tile (bank-swizzled) -> coalesced stores ----
    float bj[4];
#pragma unroll
    for (int n = 0; n < 4; ++n)
        bj[n] = BIAS ? bias[col0 + wc2 * 64 + n * 16 + (ln & 15)] : 0.f;

    char* ep = (char*)&sb[0][0];   // 32KB = full 128x128 bf16 tile
#pragma unroll
    for (int m = 0; m < 4; ++m) {
        const int rb = wr2 * 64 + m * 16 + 4 * (ln >> 4);
#pragma unroll
        for (int n = 0; n < 4; ++n) {
            const int colB = (wc2 * 64 + n * 16 + (ln & 15)) * 2;
#pragma unroll
            for (int qq = 0; qq < 4; ++qq) {
                const int rr = rb + qq;
                *(unsigned short*)(ep + rr * 256 + (colB ^ ((rr & 7) << 4))) = f2b(acc[m][n][qq] + bj[n]);
            }
        }
    }
    __syncthreads();
#pragma unroll
    for (int j = 0; j < 8; ++j) {
        const int row = t >> 1;
        const int cb = (t & 1) * 128 + j * 16;               // col byte within row
        uint4 v = *(const uint4*)(ep + row * 256 + (cb ^ ((row & 7) << 4)));
        const long r = row0 + row;
        if (r < M) *(uint4*)(Yb + r * HID + col0 + (cb >> 1)) = v;
    }
}

// ======================= CSR build (per launch) =======================
__global__ void hist_dst(const int* __restrict__ dst, int* __restrict__ deg) {
    int i = blockIdx.x * 256 + threadIdx.x;
    if (i < N_EDGES) atomicAdd(&deg[dst[i]], 1);
}

__global__ __launch_bounds__(1024) void scan_block(const int* __restrict__ deg,
                                                   int* __restrict__ sexc,
                                                   int* __restrict__ bsum) {
    int t = threadIdx.x, gid = blockIdx.x * 1024 + t;
    int v = (gid < N_NODES) ? deg[gid] : 0;
    int lane = t & 63, wv = t >> 6;
    int x = v;
#pragma unroll
    for (int o = 1; o < 64; o <<= 1) {
        int y = __shfl_up(x, o);
        if (lane >= o) x += y;
    }
    __shared__ int wsum[16];
    if (lane == 63) wsum[wv] = x;
    __syncthreads();
    if (t == 0) {
        int a = 0;
#pragma unroll
        for (int i = 0; i < 16; ++i) { int tt = wsum[i]; wsum[i] = a; a += tt; }
        bsum[blockIdx.x] = a;
    }
    __syncthreads();
    sexc[gid] = (x - v) + wsum[wv];
}

__global__ __launch_bounds__(128) void scan_partials(int* __restrict__ bsum,
                                                     int* __restrict__ offsets) {
    __shared__ int s[128];
    int t = threadIdx.x;
    int v = (t < NB) ? bsum[t] : 0;
    s[t] = v;
    __syncthreads();
    for (int o = 1; o < 128; o <<= 1) {
        int y = (t >= o) ? s[t - o] : 0;
        __syncthreads();
        s[t] += y;
        __syncthreads();
    }
    if (t < NB) bsum[t] = s[t] - v;
    if (t == 127) offsets[N_NODES] = s[127];
}

// writes offsets AND initializes cnt (= next free slot) in one pass
__global__ __launch_bounds__(1024) void scan_add(const int* __restrict__ sexc,
                                                 const int* __restrict__ bsum,
                                                 int* __restrict__ offsets,
                                                 int* __restrict__ cnt) {
    int gid = blockIdx.x * 1024 + threadIdx.x;
    if (gid < N_NODES) {
        int v = sexc[gid] + bsum[blockIdx.x];
        offsets[gid] = v;
        cnt[gid] = v;
    }
}

__global__ void csr_fill(const int* __restrict__ src, const int* __restrict__ dst,
                         int* __restrict__ cnt, int* __restrict__ csrc) {
    int i = blockIdx.x * 256 + threadIdx.x;
    if (i < N_EDGES) {
        int slot = atomicAdd(&cnt[dst[i]], 1);
        csrc[slot] = src[i];
    }
}

// goff[g] = lower_bound(graph_ids, g); graph_ids is sorted.
__global__ void graph_offsets(const int* __restrict__ gid, int* __restrict__ goff) {
    int g = blockIdx.x * 256 + threadIdx.x;
    if (g > N_GRAPHS) return;
    int lo = 0, hi = N_NODES;
    while (lo < hi) {
        int mid = (lo + hi) >> 1;
        if (gid[mid] < g) lo = mid + 1; else hi = mid;
    }
    goff[g] = lo;
}

// ===================== per-layer small kernels =====================
// el[n] = h[n]·wal, er[n] = h[n]·war for bf16 h. One wave per node.
__global__ void node_dots_b(const unsigned short* __restrict__ h,
                            const float* __restrict__ wal,
                            const float* __restrict__ war,
                            float* __restrict__ el, float* __restrict__ er) {
    int n = blockIdx.x * 4 + (threadIdx.x >> 6);
    int lane = threadIdx.x & 63;
    ushort4 zz = ((const ushort4*)(h + (size_t)n * HID))[lane];
    float4 a = ((const float4*)wal)[lane];
    float4 b = ((const float4*)war)[lane];
    float pl = b2f(zz.x) * a.x + b2f(zz.y) * a.y + b2f(zz.z) * a.z + b2f(zz.w) * a.w;
    float pr = b2f(zz.x) * b.x + b2f(zz.y) * b.y + b2f(zz.z) * b.z + b2f(zz.w) * b.w;
#pragma unroll
    for (int off = 32; off > 0; off >>= 1) {
        pl += __shfl_down(pl, off);
        pr += __shfl_down(pr, off);
    }
    if (lane == 0) { el[n] = pl; er[n] = pr; }
}

// One wave per dst node: FUSED lane-parallel segment softmax + weighted gather
// + residual + ReLU + next-layer dots. Lane i owns edge i's metadata (TWO
// coalesced loads per wave: csrc then elin — r16's 16-scalar-load form was a
// regression). Edge broadcasts use LITERAL-lane __shfl (v_readlane, SALU) via
// static unroll over edges 0..15 — no per-edge ds_bpermute (r15's defect).
// First 4 z-rows issue BEFORE the softmax reduce so the 12-shuffle chain
// hides under their latency. el/er double-buffered across layers.
__global__ __launch_bounds__(256) void gather_attn(const int* __restrict__ offs,
                                                   const int* __restrict__ csrc,
                                                   const float* __restrict__ elin,
                                                   const float* __restrict__ erin,
                                                   const unsigned short* __restrict__ z,
                                                   unsigned short* __restrict__ Ab,
                                                   const float* __restrict__ waln,
                                                   const float* __restrict__ warn,
                                                   float* __restrict__ elout,
                                                   float* __restrict__ erout) {
    const int n = blockIdx.x * 4 + (threadIdx.x >> 6);
    const int lane = threadIdx.x & 63;
    const int beg = offs[n], end = offs[n + 1];
    const int deg = end - beg;
    const float ern = erin[n];

    // lane-parallel edge metadata (lane i -> edge i): 2 coalesced loads/wave
    int se = 0; float ve = 0.f;
    const bool has = lane < deg;
    float vmax = -3.4e38f;
    if (has) {
        se = csrc[beg + lane];
        float v = elin[se] + ern;
        ve = (v >= 0.f) ? v : NEG_SLOPE * v;
        vmax = ve;
    }
    for (int i = beg + 64 + lane; i < end; i += 64) {      // deg>64: ~never
        float v = elin[csrc[i]] + ern;
        v = (v >= 0.f) ? v : NEG_SLOPE * v;
        vmax = fmaxf(vmax, v);
    }

    // broadcast first 4 sources (literal lane -> v_readlane) and early-issue
    // their z rows; the softmax reduce below overlaps these loads' latency.
    const int s0 = __shfl(se, 0), s1 = __shfl(se, 1);
    const int s2 = __shfl(se, 2), s3 = __shfl(se, 3);
    ushort4 z0 = make_ushort4(0, 0, 0, 0), z1 = make_ushort4(0, 0, 0, 0);
    ushort4 z2 = make_ushort4(0, 0, 0, 0), z3 = make_ushort4(0, 0, 0, 0);
    if (deg > 0) z0 = ((const ushort4*)(z + (size_t)s0 * HID))[lane];
    if (deg > 1) z1 = ((const ushort4*)(z + (size_t)s1 * HID))[lane];
    if (deg > 2) z2 = ((const ushort4*)(z + (size_t)s2 * HID))[lane];
    if (deg > 3) z3 = ((const ushort4*)(z + (size_t)s3 * HID))[lane];

    // softmax reduce (overlaps z-load latency)
#pragma unroll
    for (int o = 32; o > 0; o >>= 1) vmax = fmaxf(vmax, __shfl_xor(vmax, o));
    float eexp = has ? __expf(ve - vmax) : 0.f;
    float ssum = eexp;
    for (int i = beg + 64 + lane; i < end; i += 64) {      // deg>64: ~never
        float v = elin[csrc[i]] + ern;
        v = (v >= 0.f) ? v : NEG_SLOPE * v;
        ssum += __expf(v - vmax);
    }
#pragma unroll
    for (int o = 32; o > 0; o >>= 1) ssum += __shfl_xor(ssum, o);
    const float inv = 1.f / (ssum + EPS);

    // weighted gather — first 4 edges from prefetched rows
    float4 acc = make_float4(0.f, 0.f, 0.f, 0.f);
    if (deg > 0) {
        float a = __shfl(eexp, 0) * inv;
        acc.x = fmaf(a, b2f(z0.x), acc.x); acc.y = fmaf(a, b2f(z0.y), acc.y);
        acc.z = fmaf(a, b2f(z0.z), acc.z); acc.w = fmaf(a, b2f(z0.w), acc.w);
    }
    if (deg > 1) {
        float a = __shfl(eexp, 1) * inv;
        acc.x = fmaf(a, b2f(z1.x), acc.x); acc.y = fmaf(a, b2f(z1.y), acc.y);
        acc.z = fmaf(a, b2f(z1.z), acc.z); acc.w = fmaf(a, b2f(z1.w), acc.w);
    }
    if (deg > 2) {
        float a = __shfl(eexp, 2) * inv;
        acc.x = fmaf(a, b2f(z2.x), acc.x); acc.y = fmaf(a, b2f(z2.y), acc.y);
        acc.z = fmaf(a, b2f(z2.z), acc.z); acc.w = fmaf(a, b2f(z2.w), acc.w);
    }
    if (deg > 3) {
        float a = __shfl(eexp, 3) * inv;
        acc.x = fmaf(a, b2f(z3.x), acc.x); acc.y = fmaf(a, b2f(z3.y), acc.y);
        acc.z = fmaf(a, b2f(z3.z), acc.z); acc.w = fmaf(a, b2f(z3.w), acc.w);
    }
    // edges 4..15: static unroll, literal-lane broadcasts (wave-uniform guards)
    const int dfast = deg < 64 ? deg : 64;
#pragma unroll
    for (int i = 4; i < 16; ++i) {
        if (i < dfast) {
            float a = __shfl(eexp, i) * inv;
            int sc = __shfl(se, i);
            ushort4 zz = ((const ushort4*)(z + (size_t)sc * HID))[lane];
            acc.x = fmaf(a, b2f(zz.x), acc.x); acc.y = fmaf(a, b2f(zz.y), acc.y);
            acc.z = fmaf(a, b2f(zz.z), acc.z); acc.w = fmaf(a, b2f(zz.w), acc.w);
        }
    }
    // edges 16..63: dynamic (astronomically rare at Poisson(2))
    for (int c = 16; c < dfast; ++c) {
        float a = __shfl(eexp, c) * inv;
        int sc = __shfl(se, c);
        ushort4 zz = ((const ushort4*)(z + (size_t)sc * HID))[lane];
        acc.x = fmaf(a, b2f(zz.x), acc.x); acc.y = fmaf(a, b2f(zz.y), acc.y);
        acc.z = fmaf(a, b2f(zz.z), acc.z); acc.w = fmaf(a, b2f(zz.w), acc.w);
    }
    for (int cc = 64; cc < deg; ++cc) {                     // deg>64: ~never
        int sc = csrc[beg + cc];
        float v = elin[sc] + ern;
        v = (v >= 0.f) ? v : NEG_SLOPE * v;
        float a = __expf(v - vmax) * inv;
        ushort4 zz = ((const ushort4*)(z + (size_t)sc * HID))[lane];
        acc.x = fmaf(a, b2f(zz.x), acc.x); acc.y = fmaf(a, b2f(zz.y), acc.y);
        acc.z = fmaf(a, b2f(zz.z), acc.z); acc.w = fmaf(a, b2f(zz.w), acc.w);
    }

    // residual + ReLU + bf16 write
    ushort4* Ap = (ushort4*)(Ab + (size_t)n * HID);
    ushort4 hh = Ap[lane];
    float h0 = fmaxf(b2f(hh.x) + acc.x, 0.f);
    float h1 = fmaxf(b2f(hh.y) + acc.y, 0.f);
    float h2 = fmaxf(b2f(hh.z) + acc.z, 0.f);
    float h3 = fmaxf(b2f(hh.w) + acc.w, 0.f);
    ushort4 ob;
    ob.x = f2b(h0); ob.y = f2b(h1); ob.z = f2b(h2); ob.w = f2b(h3);
    Ap[lane] = ob;

    if (waln) {   // wave-uniform: next layer's attention dots into the OTHER buffer
        float4 wa = ((const float4*)waln)[lane];
        float4 wb = ((const float4*)warn)[lane];
        float pl = h0 * wa.x + h1 * wa.y + h2 * wa.z + h3 * wa.w;
        float pr = h0 * wb.x + h1 * wb.y + h2 * wb.z + h3 * wb.w;
#pragma unroll
        for (int o = 32; o > 0; o >>= 1) {
            pl += __shfl_down(pl, o);
            pr += __shfl_down(pr, o);
        }
        if (lane == 0) { elout[n] = pl; erout[n] = pr; }
    }
}

// g[gi,:] = sum of bf16 h rows in [goff[gi], goff[gi+1]) — sorted, no atomics
__global__ __launch_bounds__(256) void pool_seg(const unsigned short* __restrict__ h,
                                                const int* __restrict__ goff,
                                                float* __restrict__ g) {
    const int gi = blockIdx.x, t = threadIdx.x;
    const int beg = goff[gi], end = goff[gi + 1];
    float acc = 0.f;
    for (int n = beg; n < end; ++n) acc += b2f(h[(size_t)n * HID + t]);
    g[(size_t)gi * HID + t] = acc;
}

// fused MLP: relu(g@w1+b1) -> relu(@w2+b2) -> @w3+b3
__global__ void mlp_kernel(const float* __restrict__ g,
                           const float* __restrict__ w1, const float* __restrict__ b1,
                           const float* __restrict__ w2, const float* __restrict__ b2,
                           const float* __restrict__ w3, const float* __restrict__ b3,
                           float* __restrict__ out) {
    int gi = blockIdx.x, t = threadIdx.x;
    __shared__ float x[HID];
    __shared__ float y1[HID / 2];
    __shared__ float y2[HID / 4];
    x[t] = g[gi * HID + t];
    __syncthreads();
    if (t < HID / 2) {
        float a = b1[t];
#pragma unroll 8
        for (int k = 0; k < HID; ++k) a += x[k] * w1[k * (HID / 2) + t];
        y1[t] = fmaxf(a, 0.f);
    }
    __syncthreads();
    if (t < HID / 4) {
        float a = b2[t];
#pragma unroll 8
        for (int k = 0; k < HID / 2; ++k) a += y1[k] * w2[k * (HID / 4) + t];
        y2[t] = fmaxf(a, 0.f);
    }
    __syncthreads();
    if (t < 64) {
        float p = y2[t] * w3[t];
#pragma unroll
        for (int off = 32; off > 0; off >>= 1) p += __shfl_down(p, off);
        if (t == 0) out[gi] = p + b3[0];
    }
}

extern "C" void kernel_launch(void* const* d_in, const int* in_sizes, int n_in,
                              void* d_out, int out_size, void* d_ws, size_t ws_size,
                              hipStream_t stream) {
    const float* node_feats = (const float*)d_in[0];
    const int*   src        = (const int*)d_in[1];
    const int*   dst        = (const int*)d_in[2];
    const int*   graph_ids  = (const int*)d_in[3];
    const float* w_embed    = (const float*)d_in[4];
    const float* b_embed    = (const float*)d_in[5];
    const float* gat_W      = (const float*)d_in[6];
    const float* gat_al     = (const float*)d_in[7];
    const float* gat_ar     = (const float*)d_in[8];
    const float* w1         = (const float*)d_in[9];
    const float* b1         = (const float*)d_in[10];
    const float* w2         = (const float*)d_in[11];
    const float* b2         = (const float*)d_in[12];
    const float* w3         = (const float*)d_in[13];
    const float* b3         = (const float*)d_in[14];
    float* out = (float*)d_out;

    char* ws = (char*)d_ws;
    size_t off = 0;
    auto alloc = [&](size_t bytes) { char* p = ws + off; off += (bytes + 255) & ~size_t(255); return p; };
    unsigned short* Ab      = (unsigned short*)alloc((size_t)N_NODES * HID * 2); // h (bf16)
    unsigned short* Zb      = (unsigned short*)alloc((size_t)N_NODES * HID * 2); // z (bf16); aliases nfb
    unsigned short* Wte     = (unsigned short*)alloc((size_t)HID * NODE_DIM * 2);// embed W^T bf16
    unsigned short* Wtg     = (unsigned short*)alloc((size_t)N_GAT * HID * HID * 2); // GAT W^T bf16 (all layers)
    float*          wal     = (float*)alloc((size_t)N_GAT * HID * 4);            // W@al per layer
    float*          war     = (float*)alloc((size_t)N_GAT * HID * 4);            // W@ar per layer
    float*          eler0   = (float*)alloc((size_t)2 * N_NODES * 4);            // el|er buffer A
    float*          eler1   = (float*)alloc((size_t)2 * N_NODES * 4);            // el|er buffer B
    int*            deg     = (int*)alloc((size_t)N_NODES * 4);
    int*            cnt     = (int*)alloc((size_t)N_NODES * 4);
    int*            sexc    = (int*)alloc((size_t)NB * 1024 * 4);
    int*            bsum    = (int*)alloc(128 * 4);
    int*            offsets = (int*)alloc((size_t)(N_NODES + 1) * 4);
    int*            csrc    = (int*)alloc((size_t)N_EDGES * 4);
    int*            goff    = (int*)alloc((size_t)(N_GRAPHS + 1) * 4);
    float*          g       = (float*)alloc((size_t)N_GRAPHS * HID * 4);
    float*          el0 = eler0,          *er0 = eler0 + N_NODES;
    float*          el1 = eler1,          *er1 = eler1 + N_NODES;
    unsigned short* nfb     = Zb;  // node_feats bf16, dead before Zb first written

    // ---- CSR build + graph offsets (graph static across layers) ----
    hipMemsetAsync(deg, 0, (size_t)N_NODES * 4, stream);
    hist_dst<<<(N_EDGES + 255) / 256, 256, 0, stream>>>(dst, deg);
    scan_block<<<NB, 1024, 0, stream>>>(deg, sexc, bsum);
    scan_partials<<<1, 128, 0, stream>>>(bsum, offsets);
    scan_add<<<NB, 1024, 0, stream>>>(sexc, bsum, offsets, cnt);
    csr_fill<<<(N_EDGES + 255) / 256, 256, 0, stream>>>(src, dst, cnt, csrc);
    graph_offsets<<<(N_GRAPHS + 256) / 256, 256, 0, stream>>>(graph_ids, goff);

    // ---- all weight prep up front ----
    transpose_bf16<<<dim3(NODE_DIM / 32, HID / 32, 1), 256, 0, stream>>>(w_embed, Wte, NODE_DIM);
    transpose_bf16<<<dim3(HID / 32, HID / 32, N_GAT), 256, 0, stream>>>(gat_W, Wtg, HID);
    precompute_av<<<N_GAT, 256, 0, stream>>>(Wtg, gat_al, gat_ar, wal, war);
    convert_f32_bf16<<<(N_NODES * NODE_DIM / 4 + 255) / 256, 256, 0, stream>>>(node_feats, nfb, N_NODES * NODE_DIM / 4);

    const int ntm = (N_NODES + 127) / 128;       // 782 M-tiles
    const int ngrid = ntm * 2;                   // x2 column halves (1D, swizzled)

    // ---- embed: h = nf @ w_embed + b; then layer-0 el/er (buffer A) ----
    gemm_mfma<NODE_DIM, true><<<ngrid, 256, 0, stream>>>(nfb, Wte, b_embed, Ab, N_NODES);
    node_dots_b<<<N_NODES / 4, 256, 0, stream>>>(Ab, wal, war, el0, er0);

    for (int l = 0; l < N_GAT; ++l) {
        gemm_mfma<HID, false><<<ngrid, 256, 0, stream>>>(
            Ab, Wtg + (size_t)l * HID * HID, nullptr, Zb, N_NODES);
        const bool odd = (l & 1);
        const float* elin = odd ? el1 : el0;
        const float* erin = odd ? er1 : er0;
        float* elout = odd ? el0 : el1;
        float* erout = odd ? er0 : er1;
        const float* waln = (l < N_GAT - 1) ? wal + (l + 1) * HID : nullptr;
        const float* warn = (l < N_GAT - 1) ? war + (l + 1) * HID : nullptr;
        gather_attn<<<N_NODES / 4, 256, 0, stream>>>(offsets, csrc, elin, erin, Zb, Ab,
                                                     waln, warn, elout, erout);
    }

    pool_seg<<<N_GRAPHS, 256, 0, stream>>>(Ab, goff, g);
    mlp_kernel<<<N_GRAPHS, HID, 0, stream>>>(g, w1, b1, w2, b2, w3, b3, out);
}

// Round 18
// 488.985 us; speedup vs baseline: 1.1354x; 1.0175x over previous
//
#include <hip/hip_runtime.h>
#include <hip/hip_bf16.h>

#define N_NODES 100000
#define N_EDGES 200000
#define N_GRAPHS 4096
#define NODE_DIM 64
#define HID 256
#define N_GAT 4
#define NEG_SLOPE 0.2f
#define EPS 1e-9f
#define NB 98  // ceil(N_NODES/1024)

typedef const __attribute__((address_space(1))) void gv_t;
typedef __attribute__((address_space(3))) void lv_t;
typedef __attribute__((ext_vector_type(8))) short bf16x8;
typedef __attribute__((ext_vector_type(4))) float f32x4;

__device__ __forceinline__ float b2f(unsigned short u) {
    return __uint_as_float(((unsigned)u) << 16);
}
__device__ __forceinline__ unsigned short f2b(float f) {   // RNE
    unsigned u = __float_as_uint(f);
    return (unsigned short)((u + 0x7fffu + ((u >> 16) & 1u)) >> 16);
}

// ==================== converters ====================
__global__ void convert_f32_bf16(const float* __restrict__ src,
                                 unsigned short* __restrict__ dst, int n4) {
    int i = blockIdx.x * 256 + threadIdx.x;
    if (i >= n4) return;
    float4 v = ((const float4*)src)[i];
    ushort4 o;
    o.x = f2b(v.x); o.y = f2b(v.y); o.z = f2b(v.z); o.w = f2b(v.w);
    ((ushort4*)dst)[i] = o;
}

// Wt[c][k] = bf16(W[k][c]);  W is [K][256], Wt is [256][K].  blockIdx.z = layer.
__global__ __launch_bounds__(256) void transpose_bf16(const float* __restrict__ W0,
                                                      unsigned short* __restrict__ Wt0,
                                                      int K) {
    const float* W = W0 + (size_t)blockIdx.z * K * HID;
    unsigned short* Wt = Wt0 + (size_t)blockIdx.z * K * HID;
    __shared__ float tile[32][33];
    const int kb = blockIdx.x * 32, cb = blockIdx.y * 32;
    const int tr = threadIdx.x >> 5, tc = threadIdx.x & 31;
#pragma unroll
    for (int i = 0; i < 4; ++i)
        tile[tr + i * 8][tc] = W[(size_t)(kb + tr + i * 8) * HID + cb + tc];
    __syncthreads();
#pragma unroll
    for (int i = 0; i < 4; ++i)
        Wt[(size_t)(cb + tr + i * 8) * K + kb + tc] = f2b(tile[tc][tr + i * 8]);
}

// wal[l][k] = sum_c Wt[l][c][k]*al[l][c]  (el = z@al = h@(W@al)); same for war.
__global__ __launch_bounds__(256) void precompute_av(const unsigned short* __restrict__ Wt4,
                                                     const float* __restrict__ gal,
                                                     const float* __restrict__ gar,
                                                     float* __restrict__ wal,
                                                     float* __restrict__ war) {
    const int l = blockIdx.x, k = threadIdx.x;
    const unsigned short* Wt = Wt4 + (size_t)l * HID * HID;
    const float* al = gal + l * HID;
    const float* ar = gar + l * HID;
    float a = 0.f, b = 0.f;
    for (int c = 0; c < HID; ++c) {
        float w = b2f(Wt[(size_t)c * HID + k]);
        a = fmaf(w, al[c], a);
        b = fmaf(w, ar[c], b);
    }
    wal[l * HID + k] = a;
    war[l * HID + k] = b;
}

// ==================== MFMA GEMM ====================
// Y[M,256] = X[M,K](bf16) @ Wt[256,K](bf16, pre-transposed) (+bias).
// 128x128 block tile, 4 waves (64x64 each), 4x4 frags of 16x16x32 bf16 MFMA.
// SINGLE-buffered LDS (32KB) -> 5 blocks/CU; natural VGPR allocation (88).
// 1D grid, bijective XCD swizzle, col-half = fast bit (L2 X-reuse).
// Epilogue: acc -> bank-swizzled LDS bf16 tile (32KB scratch) -> 16B stores.
template <int K, bool BIAS>
__global__ __launch_bounds__(256) void gemm_mfma(const unsigned short* __restrict__ Xb,
                                                 const unsigned short* __restrict__ Wt,
                                                 const float* __restrict__ bias,
                                                 unsigned short* __restrict__ Yb,
                                                 int M) {
    constexpr int KC = 64;
    constexpr int NT = K / KC;
    __shared__ unsigned short sb[2][128 * KC];   // [0]=X tile, [1]=W tile; 32KB total
    const int t = threadIdx.x, wv = t >> 6, ln = t & 63;
    const int wr2 = wv >> 1, wc2 = wv & 1;       // wave quadrant (2x2)

    // bijective XCD swizzle of flattened block id (m204 formula)
    const int nwg = gridDim.x;
    const int q8 = nwg >> 3, r8 = nwg & 7;
    const int xcd = blockIdx.x & 7, idx = blockIdx.x >> 3;
    const int sw = (xcd < r8) ? xcd * (q8 + 1) + idx : r8 * (q8 + 1) + (xcd - r8) * q8 + idx;
    const long row0 = (long)(sw >> 1) * 128;
    const int  col0 = (sw & 1) * 128;

    f32x4 acc[4][4];
#pragma unroll
    for (int m = 0; m < 4; ++m)
#pragma unroll
        for (int n = 0; n < 4; ++n) acc[m][n] = (f32x4){0.f, 0.f, 0.f, 0.f};

#pragma unroll
    for (int tt = 0; tt < NT; ++tt) {
        const int k0 = tt * KC;
        // ---- stage X + W tiles (16 chunks of 1KB each, 4/wave) ----
#pragma unroll
        for (int i = 0; i < 4; ++i) {
            const int chunk = wv * 4 + i;
            const int row = chunk * 8 + (ln >> 3);
            const int gsrc = (ln & 7) ^ (row & 7);
            long gr = row0 + row; if (gr >= M) gr = M - 1;
            const unsigned short* gp = Xb + gr * K + k0 + gsrc * 8;
            __builtin_amdgcn_global_load_lds((gv_t*)gp, (lv_t*)(&sb[0][chunk * 512 + ln * 8]), 16, 0, 0);
        }
#pragma unroll
        for (int i = 0; i < 4; ++i) {
            const int chunk = wv * 4 + i;
            const int row = chunk * 8 + (ln >> 3);
            const int gsrc = (ln & 7) ^ (row & 7);
            const unsigned short* gp = Wt + (size_t)(col0 + row) * K + k0 + gsrc * 8;
            __builtin_amdgcn_global_load_lds((gv_t*)gp, (lv_t*)(&sb[1][chunk * 512 + ln * 8]), 16, 0, 0);
        }
        __syncthreads();   // drain staging

#pragma unroll
        for (int kk = 0; kk < 2; ++kk) {
            bf16x8 a[4], b[4];
            const int g = kk * 4 + (ln >> 4);
#pragma unroll
            for (int m = 0; m < 4; ++m) {
                const int row = wr2 * 64 + m * 16 + (ln & 15);
                const int s = g ^ (row & 7);
                a[m] = *(const bf16x8*)&sb[0][row * 64 + s * 8];
            }
#pragma unroll
            for (int n = 0; n < 4; ++n) {
                const int row = wc2 * 64 + n * 16 + (ln & 15);
                const int s = g ^ (row & 7);
                b[n] = *(const bf16x8*)&sb[1][row * 64 + s * 8];
            }
#pragma unroll
            for (int m = 0; m < 4; ++m)
#pragma unroll
                for (int n = 0; n < 4; ++n)
                    acc[m][n] = __builtin_amdgcn_mfma_f32_16x16x32_bf16(a[m], b[n], acc[m][n], 0, 0, 0);
        }
        __syncthreads();   // protect buffer reuse (next stage / epilogue)
    }

    // ---- epilogue: acc -> LDS bf16 tile (bank-swizzled) -> coalesced stores ----
    float bj[4];
#pragma unroll
    for (int n = 0; n < 4; ++n)
        bj[n] = BIAS ? bias[col0 + wc2 * 64 + n * 16 + (ln & 15)] : 0.f;

    char* ep = (char*)&sb[0][0];   // 32KB = full 128x128 bf16 tile
#pragma unroll
    for (int m = 0; m < 4; ++m) {
        const int rb = wr2 * 64 + m * 16 + 4 * (ln >> 4);
#pragma unroll
        for (int n = 0; n < 4; ++n) {
            const int colB = (wc2 * 64 + n * 16 + (ln & 15)) * 2;
#pragma unroll
            for (int qq = 0; qq < 4; ++qq) {
                const int rr = rb + qq;
                *(unsigned short*)(ep + rr * 256 + (colB ^ ((rr & 7) << 4))) = f2b(acc[m][n][qq] + bj[n]);
            }
        }
    }
    __syncthreads();
#pragma unroll
    for (int j = 0; j < 8; ++j) {
        const int row = t >> 1;
        const int cb = (t & 1) * 128 + j * 16;               // col byte within row
        uint4 v = *(const uint4*)(ep + row * 256 + (cb ^ ((row & 7) << 4)));
        const long r = row0 + row;
        if (r < M) *(uint4*)(Yb + r * HID + col0 + (cb >> 1)) = v;
    }
}

// ======================= CSR build (per launch) =======================
__global__ void hist_dst(const int* __restrict__ dst, int* __restrict__ deg) {
    int i = blockIdx.x * 256 + threadIdx.x;
    if (i < N_EDGES) atomicAdd(&deg[dst[i]], 1);
}

__global__ __launch_bounds__(1024) void scan_block(const int* __restrict__ deg,
                                                   int* __restrict__ sexc,
                                                   int* __restrict__ bsum) {
    int t = threadIdx.x, gid = blockIdx.x * 1024 + t;
    int v = (gid < N_NODES) ? deg[gid] : 0;
    int lane = t & 63, wv = t >> 6;
    int x = v;
#pragma unroll
    for (int o = 1; o < 64; o <<= 1) {
        int y = __shfl_up(x, o);
        if (lane >= o) x += y;
    }
    __shared__ int wsum[16];
    if (lane == 63) wsum[wv] = x;
    __syncthreads();
    if (t == 0) {
        int a = 0;
#pragma unroll
        for (int i = 0; i < 16; ++i) { int tt = wsum[i]; wsum[i] = a; a += tt; }
        bsum[blockIdx.x] = a;
    }
    __syncthreads();
    sexc[gid] = (x - v) + wsum[wv];
}

__global__ __launch_bounds__(128) void scan_partials(int* __restrict__ bsum,
                                                     int* __restrict__ offsets) {
    __shared__ int s[128];
    int t = threadIdx.x;
    int v = (t < NB) ? bsum[t] : 0;
    s[t] = v;
    __syncthreads();
    for (int o = 1; o < 128; o <<= 1) {
        int y = (t >= o) ? s[t - o] : 0;
        __syncthreads();
        s[t] += y;
        __syncthreads();
    }
    if (t < NB) bsum[t] = s[t] - v;
    if (t == 127) offsets[N_NODES] = s[127];
}

// writes offsets AND initializes cnt (= next free slot) in one pass
__global__ __launch_bounds__(1024) void scan_add(const int* __restrict__ sexc,
                                                 const int* __restrict__ bsum,
                                                 int* __restrict__ offsets,
                                                 int* __restrict__ cnt) {
    int gid = blockIdx.x * 1024 + threadIdx.x;
    if (gid < N_NODES) {
        int v = sexc[gid] + bsum[blockIdx.x];
        offsets[gid] = v;
        cnt[gid] = v;
    }
}

__global__ void csr_fill(const int* __restrict__ src, const int* __restrict__ dst,
                         int* __restrict__ cnt, int* __restrict__ csrc) {
    int i = blockIdx.x * 256 + threadIdx.x;
    if (i < N_EDGES) {
        int slot = atomicAdd(&cnt[dst[i]], 1);
        csrc[slot] = src[i];
    }
}

// goff[g] = lower_bound(graph_ids, g); graph_ids is sorted.
__global__ void graph_offsets(const int* __restrict__ gid, int* __restrict__ goff) {
    int g = blockIdx.x * 256 + threadIdx.x;
    if (g > N_GRAPHS) return;
    int lo = 0, hi = N_NODES;
    while (lo < hi) {
        int mid = (lo + hi) >> 1;
        if (gid[mid] < g) lo = mid + 1; else hi = mid;
    }
    goff[g] = lo;
}

// ===================== per-layer small kernels =====================
// el[n] = h[n]·wal, er[n] = h[n]·war for bf16 h. One wave per node.
__global__ void node_dots_b(const unsigned short* __restrict__ h,
                            const float* __restrict__ wal,
                            const float* __restrict__ war,
                            float* __restrict__ el, float* __restrict__ er) {
    int n = blockIdx.x * 4 + (threadIdx.x >> 6);
    int lane = threadIdx.x & 63;
    ushort4 zz = ((const ushort4*)(h + (size_t)n * HID))[lane];
    float4 a = ((const float4*)wal)[lane];
    float4 b = ((const float4*)war)[lane];
    float pl = b2f(zz.x) * a.x + b2f(zz.y) * a.y + b2f(zz.z) * a.z + b2f(zz.w) * a.w;
    float pr = b2f(zz.x) * b.x + b2f(zz.y) * b.y + b2f(zz.z) * b.z + b2f(zz.w) * b.w;
#pragma unroll
    for (int off = 32; off > 0; off >>= 1) {
        pl += __shfl_down(pl, off);
        pr += __shfl_down(pr, off);
    }
    if (lane == 0) { el[n] = pl; er[n] = pr; }
}

// One wave per dst node: FUSED lane-parallel segment softmax + weighted gather
// + residual + ReLU + next-layer dots. Lane i owns edge i's (src, el) for the
// softmax; z loads for the first two edges issue BEFORE the shuffle reduce so
// the 12-shfl+exp chain hides under their latency. el/er are double-buffered
// across layers (elin/erin read-only here; elout/erout written at the end)
// to avoid the intra-kernel read/write race that fusing creates.
__global__ __launch_bounds__(256) void gather_attn(const int* __restrict__ offs,
                                                   const int* __restrict__ csrc,
                                                   const float* __restrict__ elin,
                                                   const float* __restrict__ erin,
                                                   const unsigned short* __restrict__ z,
                                                   unsigned short* __restrict__ Ab,
                                                   const float* __restrict__ waln,
                                                   const float* __restrict__ warn,
                                                   float* __restrict__ elout,
                                                   float* __restrict__ erout) {
    const int n = blockIdx.x * 4 + (threadIdx.x >> 6);
    const int lane = threadIdx.x & 63;
    const int beg = offs[n], end = offs[n + 1];
    const int deg = end - beg;
    const float ern = erin[n];

    // lane-parallel edge metadata (lane i -> edge i)
    int se = 0; float ve = 0.f;
    const bool has = lane < deg;
    float vmax = -3.4e38f;
    if (has) {
        se = csrc[beg + lane];
        float v = elin[se] + ern;
        ve = (v >= 0.f) ? v : NEG_SLOPE * v;
        vmax = ve;
    }
    for (int i = beg + 64 + lane; i < end; i += 64) {      // deg>64: rare
        float v = elin[csrc[i]] + ern;
        v = (v >= 0.f) ? v : NEG_SLOPE * v;
        vmax = fmaxf(vmax, v);
    }

    // early-issue z loads for the first two edges (dominant case)
    const int s0 = __shfl(se, 0);
    const int s1 = __shfl(se, 1);
    ushort4 z0 = make_ushort4(0, 0, 0, 0), z1 = make_ushort4(0, 0, 0, 0);
    if (deg > 0) z0 = ((const ushort4*)(z + (size_t)s0 * HID))[lane];
    if (deg > 1) z1 = ((const ushort4*)(z + (size_t)s1 * HID))[lane];

    // softmax reduce (overlaps z-load latency)
#pragma unroll
    for (int o = 32; o > 0; o >>= 1) vmax = fmaxf(vmax, __shfl_xor(vmax, o));
    float eexp = has ? __expf(ve - vmax) : 0.f;
    float ssum = eexp;
    for (int i = beg + 64 + lane; i < end; i += 64) {      // deg>64: rare
        float v = elin[csrc[i]] + ern;
        v = (v >= 0.f) ? v : NEG_SLOPE * v;
        ssum += __expf(v - vmax);
    }
#pragma unroll
    for (int o = 32; o > 0; o >>= 1) ssum += __shfl_xor(ssum, o);
    const float inv = 1.f / (ssum + EPS);

    // weighted gather
    float4 acc = make_float4(0.f, 0.f, 0.f, 0.f);
    if (deg > 0) {
        float a0 = __shfl(eexp, 0) * inv;
        acc.x = fmaf(a0, b2f(z0.x), acc.x);
        acc.y = fmaf(a0, b2f(z0.y), acc.y);
        acc.z = fmaf(a0, b2f(z0.z), acc.z);
        acc.w = fmaf(a0, b2f(z0.w), acc.w);
    }
    if (deg > 1) {
        float a1 = __shfl(eexp, 1) * inv;
        acc.x = fmaf(a1, b2f(z1.x), acc.x);
        acc.y = fmaf(a1, b2f(z1.y), acc.y);
        acc.z = fmaf(a1, b2f(z1.z), acc.z);
        acc.w = fmaf(a1, b2f(z1.w), acc.w);
    }
    const int dfast = deg < 64 ? deg : 64;
    int c = 2;
    for (; c + 1 < dfast; c += 2) {
        float a0c = __shfl(eexp, c) * inv;     int sc0 = __shfl(se, c);
        float a1c = __shfl(eexp, c + 1) * inv; int sc1 = __shfl(se, c + 1);
        ushort4 za = ((const ushort4*)(z + (size_t)sc0 * HID))[lane];
        ushort4 zb = ((const ushort4*)(z + (size_t)sc1 * HID))[lane];
        acc.x = fmaf(a0c, b2f(za.x), acc.x); acc.x = fmaf(a1c, b2f(zb.x), acc.x);
        acc.y = fmaf(a0c, b2f(za.y), acc.y); acc.y = fmaf(a1c, b2f(zb.y), acc.y);
        acc.z = fmaf(a0c, b2f(za.z), acc.z); acc.z = fmaf(a1c, b2f(zb.z), acc.z);
        acc.w = fmaf(a0c, b2f(za.w), acc.w); acc.w = fmaf(a1c, b2f(zb.w), acc.w);
    }
    if (c < dfast) {
        float a = __shfl(eexp, c) * inv; int sc = __shfl(se, c);
        ushort4 zz = ((const ushort4*)(z + (size_t)sc * HID))[lane];
        acc.x = fmaf(a, b2f(zz.x), acc.x);
        acc.y = fmaf(a, b2f(zz.y), acc.y);
        acc.z = fmaf(a, b2f(zz.z), acc.z);
        acc.w = fmaf(a, b2f(zz.w), acc.w);
    }
    for (int cc = 64; cc < deg; ++cc) {                     // deg>64: rare
        int sc = csrc[beg + cc];
        float v = elin[sc] + ern;
        v = (v >= 0.f) ? v : NEG_SLOPE * v;
        float a = __expf(v - vmax) * inv;
        ushort4 zz = ((const ushort4*)(z + (size_t)sc * HID))[lane];
        acc.x = fmaf(a, b2f(zz.x), acc.x);
        acc.y = fmaf(a, b2f(zz.y), acc.y);
        acc.z = fmaf(a, b2f(zz.z), acc.z);
        acc.w = fmaf(a, b2f(zz.w), acc.w);
    }

    // residual + ReLU + bf16 write
    ushort4* Ap = (ushort4*)(Ab + (size_t)n * HID);
    ushort4 hh = Ap[lane];
    float h0 = fmaxf(b2f(hh.x) + acc.x, 0.f);
    float h1 = fmaxf(b2f(hh.y) + acc.y, 0.f);
    float h2 = fmaxf(b2f(hh.z) + acc.z, 0.f);
    float h3 = fmaxf(b2f(hh.w) + acc.w, 0.f);
    ushort4 ob;
    ob.x = f2b(h0); ob.y = f2b(h1); ob.z = f2b(h2); ob.w = f2b(h3);
    Ap[lane] = ob;

    if (waln) {   // wave-uniform: next layer's attention dots into the OTHER buffer
        float4 wa = ((const float4*)waln)[lane];
        float4 wb = ((const float4*)warn)[lane];
        float pl = h0 * wa.x + h1 * wa.y + h2 * wa.z + h3 * wa.w;
        float pr = h0 * wb.x + h1 * wb.y + h2 * wb.z + h3 * wb.w;
#pragma unroll
        for (int o = 32; o > 0; o >>= 1) {
            pl += __shfl_down(pl, o);
            pr += __shfl_down(pr, o);
        }
        if (lane == 0) { elout[n] = pl; erout[n] = pr; }
    }
}

// g[gi,:] = sum of bf16 h rows in [goff[gi], goff[gi+1]) — sorted, no atomics
__global__ __launch_bounds__(256) void pool_seg(const unsigned short* __restrict__ h,
                                                const int* __restrict__ goff,
                                                float* __restrict__ g) {
    const int gi = blockIdx.x, t = threadIdx.x;
    const int beg = goff[gi], end = goff[gi + 1];
    float acc = 0.f;
    for (int n = beg; n < end; ++n) acc += b2f(h[(size_t)n * HID + t]);
    g[(size_t)gi * HID + t] = acc;
}

// fused MLP: relu(g@w1+b1) -> relu(@w2+b2) -> @w3+b3
__global__ void mlp_kernel(const float* __restrict__ g,
                           const float* __restrict__ w1, const float* __restrict__ b1,
                           const float* __restrict__ w2, const float* __restrict__ b2,
                           const float* __restrict__ w3, const float* __restrict__ b3,
                           float* __restrict__ out) {
    int gi = blockIdx.x, t = threadIdx.x;
    __shared__ float x[HID];
    __shared__ float y1[HID / 2];
    __shared__ float y2[HID / 4];
    x[t] = g[gi * HID + t];
    __syncthreads();
    if (t < HID / 2) {
        float a = b1[t];
#pragma unroll 8
        for (int k = 0; k < HID; ++k) a += x[k] * w1[k * (HID / 2) + t];
        y1[t] = fmaxf(a, 0.f);
    }
    __syncthreads();
    if (t < HID / 4) {
        float a = b2[t];
#pragma unroll 8
        for (int k = 0; k < HID / 2; ++k) a += y1[k] * w2[k * (HID / 4) + t];
        y2[t] = fmaxf(a, 0.f);
    }
    __syncthreads();
    if (t < 64) {
        float p = y2[t] * w3[t];
#pragma unroll
        for (int off = 32; off > 0; off >>= 1) p += __shfl_down(p, off);
        if (t == 0) out[gi] = p + b3[0];
    }
}

extern "C" void kernel_launch(void* const* d_in, const int* in_sizes, int n_in,
                              void* d_out, int out_size, void* d_ws, size_t ws_size,
                              hipStream_t stream) {
    const float* node_feats = (const float*)d_in[0];
    const int*   src        = (const int*)d_in[1];
    const int*   dst        = (const int*)d_in[2];
    const int*   graph_ids  = (const int*)d_in[3];
    const float* w_embed    = (const float*)d_in[4];
    const float* b_embed    = (const float*)d_in[5];
    const float* gat_W      = (const float*)d_in[6];
    const float* gat_al     = (const float*)d_in[7];
    const float* gat_ar     = (const float*)d_in[8];
    const float* w1         = (const float*)d_in[9];
    const float* b1         = (const float*)d_in[10];
    const float* w2         = (const float*)d_in[11];
    const float* b2         = (const float*)d_in[12];
    const float* w3         = (const float*)d_in[13];
    const float* b3         = (const float*)d_in[14];
    float* out = (float*)d_out;

    char* ws = (char*)d_ws;
    size_t off = 0;
    auto alloc = [&](size_t bytes) { char* p = ws + off; off += (bytes + 255) & ~size_t(255); return p; };
    unsigned short* Ab      = (unsigned short*)alloc((size_t)N_NODES * HID * 2); // h (bf16)
    unsigned short* Zb      = (unsigned short*)alloc((size_t)N_NODES * HID * 2); // z (bf16); aliases nfb
    unsigned short* Wte     = (unsigned short*)alloc((size_t)HID * NODE_DIM * 2);// embed W^T bf16
    unsigned short* Wtg     = (unsigned short*)alloc((size_t)N_GAT * HID * HID * 2); // GAT W^T bf16 (all layers)
    float*          wal     = (float*)alloc((size_t)N_GAT * HID * 4);            // W@al per layer
    float*          war     = (float*)alloc((size_t)N_GAT * HID * 4);            // W@ar per layer
    float*          eler0   = (float*)alloc((size_t)2 * N_NODES * 4);            // el|er buffer A
    float*          eler1   = (float*)alloc((size_t)2 * N_NODES * 4);            // el|er buffer B
    int*            deg     = (int*)alloc((size_t)N_NODES * 4);
    int*            cnt     = (int*)alloc((size_t)N_NODES * 4);
    int*            sexc    = (int*)alloc((size_t)NB * 1024 * 4);
    int*            bsum    = (int*)alloc(128 * 4);
    int*            offsets = (int*)alloc((size_t)(N_NODES + 1) * 4);
    int*            csrc    = (int*)alloc((size_t)N_EDGES * 4);
    int*            goff    = (int*)alloc((size_t)(N_GRAPHS + 1) * 4);
    float*          g       = (float*)alloc((size_t)N_GRAPHS * HID * 4);
    float*          el0 = eler0,          *er0 = eler0 + N_NODES;
    float*          el1 = eler1,          *er1 = eler1 + N_NODES;
    unsigned short* nfb     = Zb;  // node_feats bf16, dead before Zb first written

    // ---- CSR build + graph offsets (graph static across layers) ----
    hipMemsetAsync(deg, 0, (size_t)N_NODES * 4, stream);
    hist_dst<<<(N_EDGES + 255) / 256, 256, 0, stream>>>(dst, deg);
    scan_block<<<NB, 1024, 0, stream>>>(deg, sexc, bsum);
    scan_partials<<<1, 128, 0, stream>>>(bsum, offsets);
    scan_add<<<NB, 1024, 0, stream>>>(sexc, bsum, offsets, cnt);
    csr_fill<<<(N_EDGES + 255) / 256, 256, 0, stream>>>(src, dst, cnt, csrc);
    graph_offsets<<<(N_GRAPHS + 256) / 256, 256, 0, stream>>>(graph_ids, goff);

    // ---- all weight prep up front ----
    transpose_bf16<<<dim3(NODE_DIM / 32, HID / 32, 1), 256, 0, stream>>>(w_embed, Wte, NODE_DIM);
    transpose_bf16<<<dim3(HID / 32, HID / 32, N_GAT), 256, 0, stream>>>(gat_W, Wtg, HID);
    precompute_av<<<N_GAT, 256, 0, stream>>>(Wtg, gat_al, gat_ar, wal, war);
    convert_f32_bf16<<<(N_NODES * NODE_DIM / 4 + 255) / 256, 256, 0, stream>>>(node_feats, nfb, N_NODES * NODE_DIM / 4);

    const int ntm = (N_NODES + 127) / 128;       // 782 M-tiles
    const int ngrid = ntm * 2;                   // x2 column halves (1D, swizzled)

    // ---- embed: h = nf @ w_embed + b; then layer-0 el/er (buffer A) ----
    gemm_mfma<NODE_DIM, true><<<ngrid, 256, 0, stream>>>(nfb, Wte, b_embed, Ab, N_NODES);
    node_dots_b<<<N_NODES / 4, 256, 0, stream>>>(Ab, wal, war, el0, er0);

    for (int l = 0; l < N_GAT; ++l) {
        gemm_mfma<HID, false><<<ngrid, 256, 0, stream>>>(
            Ab, Wtg + (size_t)l * HID * HID, nullptr, Zb, N_NODES);
        const bool odd = (l & 1);
        const float* elin = odd ? el1 : el0;
        const float* erin = odd ? er1 : er0;
        float* elout = odd ? el0 : el1;
        float* erout = odd ? er0 : er1;
        const float* waln = (l < N_GAT - 1) ? wal + (l + 1) * HID : nullptr;
        const float* warn = (l < N_GAT - 1) ? war + (l + 1) * HID : nullptr;
        gather_attn<<<N_NODES / 4, 256, 0, stream>>>(offsets, csrc, elin, erin, Zb, Ab,
                                                     waln, warn, elout, erout);
    }

    pool_seg<<<N_GRAPHS, 256, 0, stream>>>(Ab, goff, g);
    mlp_kernel<<<N_GRAPHS, HID, 0, stream>>>(g, w1, b1, w2, b2, w3, b3, out);
}